// Round 8
// baseline (278.543 us; speedup 1.0000x reference)
//
#include <hip/hip_runtime.h>
#include <hip/hip_bf16.h>

#define DIM 768
#define NB 16
#define NPOS 4096
#define HEADS 12

typedef unsigned short u16;
typedef __attribute__((ext_vector_type(4))) float f32x4;
typedef __attribute__((ext_vector_type(8))) short s16x8;
typedef __attribute__((ext_vector_type(4))) u16 u16x4;

static __device__ __forceinline__ u16 f2bf(float f) {
  __hip_bfloat16 h = __float2bfloat16(f);
  u16 u; __builtin_memcpy(&u, &h, 2); return u;
}
static __device__ __forceinline__ float bf2f(u16 u) {
  unsigned int x = ((unsigned int)u) << 16;
  float f; __builtin_memcpy(&f, &x, 4); return f;
}

// async global->LDS, 16B per lane; LDS dest = wave-uniform base + lane*16
static __device__ __forceinline__ void load_lds16(const void* g, void* l) {
  __builtin_amdgcn_global_load_lds(
      (const __attribute__((address_space(1))) unsigned int*)g,
      (__attribute__((address_space(3))) unsigned int*)l, 16, 0, 0);
}

// LDS tile layout: [rows][64 bf16], fully LINEAR (row*128B + slot*16B).
// NOTE: no XOR swizzle — a per-lane 16B source permutation defeats the
// global_load_lds coalescer (~8 B/cyc/CU vs 21.6 linear, R2-R7 vs m97).
// The resulting 16-way ds_read bank conflict is the cheaper side (m97/m98).
static __device__ __forceinline__ int lds_idx(int row, int slotf) {
  return row * 64 + (slotf << 3);   // ushort units
}

// ---------------- BN stats + fused cast to bf16 ----------------

__global__ __launch_bounds__(128) void sums_cast_kernel(const float* __restrict__ x,
                                                        float* __restrict__ sum_bc,
                                                        float* __restrict__ sumsq_bc,
                                                        u16* __restrict__ Xb) {
  int bc = blockIdx.x;  // b*DIM + c
  const float4* p = (const float4*)(x + (size_t)bc * NPOS);
  u16x4* ob = (u16x4*)(Xb + (size_t)bc * NPOS);
  int t = threadIdx.x;
  float s = 0.f, ss = 0.f;
  for (int i = t; i < NPOS / 4; i += 128) {
    float4 v = p[i];
    s  += v.x + v.y + v.z + v.w;
    ss += v.x * v.x + v.y * v.y + v.z * v.z + v.w * v.w;
    u16x4 hv = {f2bf(v.x), f2bf(v.y), f2bf(v.z), f2bf(v.w)};
    ob[i] = hv;
  }
  for (int off = 32; off; off >>= 1) { s += __shfl_down(s, off); ss += __shfl_down(ss, off); }
  __shared__ float red[4];
  int lane = t & 63, w = t >> 6;
  if (lane == 0) { red[w] = s; red[2 + w] = ss; }
  __syncthreads();
  if (t == 0) { sum_bc[bc] = red[0] + red[1]; sumsq_bc[bc] = red[2] + red[3]; }
}

__global__ void finalize_kernel(const float* __restrict__ sum_bc, const float* __restrict__ sumsq_bc,
                                const float* __restrict__ gamma, const float* __restrict__ beta,
                                float* __restrict__ chanScale, float* __restrict__ chanShift) {
  int c = blockIdx.x * blockDim.x + threadIdx.x;
  if (c >= DIM) return;
  float s = 0.f, ss = 0.f;
  for (int b = 0; b < NB; b++) { s += sum_bc[b * DIM + c]; ss += sumsq_bc[b * DIM + c]; }
  const float invn = 1.f / ((float)NB * (float)NPOS);
  float mean = s * invn;
  float var  = ss * invn - mean * mean;
  float rstd = rsqrtf(var + 1e-5f);
  float a = rstd * gamma[c];
  chanScale[c] = a;
  chanShift[c] = beta[c] - mean * a;
}

// standalone BN apply (fallback path only): reads fp32 x
__global__ __launch_bounds__(256) void bn_kernel(const float* __restrict__ x,
                                                 const float* __restrict__ chanScale,
                                                 const float* __restrict__ chanShift,
                                                 float* __restrict__ out) {
  const size_t n4 = (size_t)NB * DIM * NPOS / 4;
  const float4* x4 = (const float4*)x;
  float4* o4 = (float4*)out;
  for (size_t i = (size_t)blockIdx.x * blockDim.x + threadIdx.x; i < n4;
       i += (size_t)gridDim.x * blockDim.x) {
    float4 v = x4[i];
    int c = (int)((i >> 10) % DIM);
    float a = chanScale[c], sh = chanShift[c];
    v.x = fmaxf(fmaf(v.x, a, sh), 0.f);
    v.y = fmaxf(fmaf(v.y, a, sh), 0.f);
    v.z = fmaxf(fmaf(v.z, a, sh), 0.f);
    v.w = fmaxf(fmaf(v.w, a, sh), 0.f);
    o4[i] = v;
  }
}

// ------------- tvec (t[b][r] = W[r,:]·s_b) + fused cast of W rows 0..1535 -------------

__global__ __launch_bounds__(64) void tvecw_kernel(const float* __restrict__ W,
                                                   const float* __restrict__ sum_bc,
                                                   float* __restrict__ tvec,
                                                   u16* __restrict__ Wb) {
  int r = blockIdx.x;   // 0..1535
  int lane = threadIdx.x;
  const float* wr = W + (size_t)r * DIM;
  float acc[NB];
#pragma unroll
  for (int b = 0; b < NB; b++) acc[b] = 0.f;
#pragma unroll
  for (int j = 0; j < DIM / 64; j++) {
    int c = lane + j * 64;
    float wv = wr[c];
    Wb[(size_t)r * DIM + c] = f2bf(wv);
#pragma unroll
    for (int b = 0; b < NB; b++) acc[b] += wv * sum_bc[b * DIM + c];
  }
#pragma unroll
  for (int b = 0; b < NB; b++) {
    float v = acc[b];
    for (int off = 32; off; off >>= 1) v += __shfl_down(v, off);
    if (lane == 0) tvec[(size_t)b * 1536 + r] = v;
  }
}

// ------- bf16 GEMM C = A·B^T, 128x128 tile, BK=64, counted-vmcnt 2-phase pipeline ----
// SYMM: 1-D grid; first nGram blocks enumerate tile pairs ti<=tj (XCD-swizzled:
// each XCD gets 2 whole batches -> L2 panel locality); write C and C^T; blocks
// >= nGram run a grid-stride BN-apply (HBM-bound work overlapped with gram).

template <bool SYMM>
__global__ __launch_bounds__(256) void gemm_kernel(
    const u16* __restrict__ A, long long strideA,
    const u16* __restrict__ B, long long strideB,
    u16* __restrict__ C, long long strideC,
    int lda, int ldb, int ldc, int K, int nGram,
    const u16* __restrict__ XbBn, const float* __restrict__ chanScale,
    const float* __restrict__ chanShift, float* __restrict__ outY) {
  __shared__ __align__(16) u16 As[2][128 * 64];
  __shared__ __align__(16) u16 Bs[2][128 * 64];

  int ti, tj, bz;
  if (SYMM) {
    if ((int)blockIdx.x >= nGram) {
      // ---- fused BN apply: y = relu(Xb*scale + shift), bf16 in / fp32 out ----
      int t = threadIdx.x;
      const size_t total8 = (size_t)NB * DIM * NPOS / 8;
      size_t stride = (size_t)(gridDim.x - nGram) * 256;
      const s16x8* xs = (const s16x8*)XbBn;
      float4* o4 = (float4*)outY;
      for (size_t i = (size_t)(blockIdx.x - nGram) * 256 + t; i < total8; i += stride) {
        s16x8 v = xs[i];
        int c = (int)((i >> 9) % DIM);   // 512 groups of 8 per (b,c) plane
        float a = chanScale[c], sh = chanShift[c];
        float4 o0, o1;
        o0.x = fmaxf(fmaf(bf2f((u16)v[0]), a, sh), 0.f);
        o0.y = fmaxf(fmaf(bf2f((u16)v[1]), a, sh), 0.f);
        o0.z = fmaxf(fmaf(bf2f((u16)v[2]), a, sh), 0.f);
        o0.w = fmaxf(fmaf(bf2f((u16)v[3]), a, sh), 0.f);
        o1.x = fmaxf(fmaf(bf2f((u16)v[4]), a, sh), 0.f);
        o1.y = fmaxf(fmaf(bf2f((u16)v[5]), a, sh), 0.f);
        o1.z = fmaxf(fmaf(bf2f((u16)v[6]), a, sh), 0.f);
        o1.w = fmaxf(fmaf(bf2f((u16)v[7]), a, sh), 0.f);
        o4[2 * i] = o0;
        o4[2 * i + 1] = o1;
      }
      return;
    }
    int bid = blockIdx.x;                       // nGram = 336, 336%8==0
    int swz = (bid & 7) * 42 + (bid >> 3);      // bijective XCD swizzle
    bz = swz / 21;
    int idx = swz % 21, rem = 6;
    ti = 0;
    while (idx >= rem) { idx -= rem; ti++; rem--; }
    tj = ti + idx;
  } else {
    ti = blockIdx.x; tj = blockIdx.y; bz = blockIdx.z;
  }
  const u16* Ab = A + (size_t)bz * strideA;
  const u16* Bb = B + (size_t)bz * strideB;
  u16* Cb = C + (size_t)bz * strideC;
  int ib = ti * 128, jb = tj * 128;

  int t = threadIdx.x, lane = t & 63, w = t >> 6;
  int wr = (w >> 1) * 64, wc = (w & 1) * 64;
  int fr = lane & 15, q4 = lane >> 4;
  int srow = lane >> 3;
  int sslot = lane & 7;   // LINEAR source slot (no XOR)

  // per-wave staging source base offsets (row = q*8+srow, q = w*4+i)
  const u16* Asrc = Ab + (size_t)(ib + srow) * lda + sslot * 8;
  const u16* Bsrc = Bb + (size_t)(jb + srow) * ldb + sslot * 8;

  f32x4 acc[4][4];
#pragma unroll
  for (int m = 0; m < 4; m++)
#pragma unroll
    for (int n = 0; n < 4; n++) acc[m][n] = (f32x4){0.f, 0.f, 0.f, 0.f};

#define STAGE(buf, k0)                                                          \
  {                                                                             \
    _Pragma("unroll")                                                           \
    for (int i = 0; i < 4; i++) {                                               \
      int q = w * 4 + i;   /* 8 global_load_lds per wave per buffer */          \
      load_lds16(Asrc + (size_t)(q * 8) * lda + (k0), (char*)As[buf] + q * 1024);\
      load_lds16(Bsrc + (size_t)(q * 8) * ldb + (k0), (char*)Bs[buf] + q * 1024);\
    }                                                                           \
  }

#define COMPUTE(buf)                                                            \
  {                                                                             \
    _Pragma("unroll")                                                           \
    for (int kk = 0; kk < 2; kk++) {                                            \
      int sbase = kk * 4 + q4;                                                  \
      s16x8 af[4], bfv[4];                                                      \
      _Pragma("unroll")                                                         \
      for (int m = 0; m < 4; m++) af[m] = *(const s16x8*)&As[buf][lds_idx(wr + m * 16 + fr, sbase)]; \
      _Pragma("unroll")                                                         \
      for (int n = 0; n < 4; n++) bfv[n] = *(const s16x8*)&Bs[buf][lds_idx(wc + n * 16 + fr, sbase)]; \
      _Pragma("unroll")                                                         \
      for (int m = 0; m < 4; m++)                                               \
        _Pragma("unroll")                                                       \
        for (int n = 0; n < 4; n++)                                             \
          acc[m][n] = __builtin_amdgcn_mfma_f32_16x16x32_bf16(af[m], bfv[n], acc[m][n], 0, 0, 0); \
    }                                                                           \
  }

  // Counted-vmcnt 2-phase pipeline (T3/T4): never drain the just-issued
  // prefetch; vmcnt(8) waits only the PREVIOUS step's 8 loads.
  const int nt = K >> 6;   // even for all uses (64, 12)
  STAGE(0, 0);
  for (int t2 = 0; t2 < nt; t2 += 2) {
    STAGE(1, (t2 + 1) << 6);
    asm volatile("s_waitcnt vmcnt(8)" ::: "memory");
    __builtin_amdgcn_s_barrier();
    __builtin_amdgcn_sched_barrier(0);
    COMPUTE(0);
    __builtin_amdgcn_s_barrier();
    if (t2 + 2 < nt) {
      STAGE(0, (t2 + 2) << 6);
      asm volatile("s_waitcnt vmcnt(8)" ::: "memory");
    } else {
      asm volatile("s_waitcnt vmcnt(0)" ::: "memory");
    }
    __builtin_amdgcn_s_barrier();
    __builtin_amdgcn_sched_barrier(0);
    COMPUTE(1);
    __builtin_amdgcn_s_barrier();
  }
#undef STAGE
#undef COMPUTE

  int rbase = q4 * 4;
#pragma unroll
  for (int m = 0; m < 4; m++)
#pragma unroll
    for (int n = 0; n < 4; n++)
#pragma unroll
      for (int r = 0; r < 4; r++) {
        int row = ib + wr + m * 16 + rbase + r;
        int col = jb + wc + n * 16 + fr;
        u16 v = f2bf(acc[m][n][r]);
        Cb[(size_t)row * ldc + col] = v;
        if (SYMM && ti != tj) Cb[(size_t)col * ldc + row] = v;
      }
}

// ---------- per-(b,h): attn = softmax(sign*sqrt(|S*(P·Wk^T + rank1)|+eps)) ----------

__global__ __launch_bounds__(256) void attn_kernel(const u16* __restrict__ Pb,
                                                   const u16* __restrict__ Wb,
                                                   const float* __restrict__ bias,
                                                   const float* __restrict__ tvec,
                                                   float* __restrict__ outAttn) {
  int h = blockIdx.x, b = blockIdx.y;
  __shared__ __align__(16) u16 As[2][64 * 64];
  __shared__ __align__(16) u16 Bs[2][64 * 64];
  __shared__ float sm[64 * 65];
  const u16* Pa = Pb + ((size_t)b * DIM + h * 64) * DIM;
  const u16* Wk = Wb + (size_t)(DIM + h * 64) * DIM;

  int t = threadIdx.x, lane = t & 63, w = t >> 6;
  int fr = lane & 15, q4 = lane >> 4;
  int srow = lane >> 3;
  int sslot = lane & 7;   // LINEAR

  const u16* Asrc = Pa + (size_t)srow * DIM + sslot * 8;
  const u16* Bsrc = Wk + (size_t)srow * DIM + sslot * 8;

  f32x4 acc[4];
#pragma unroll
  for (int n = 0; n < 4; n++) acc[n] = (f32x4){0.f, 0.f, 0.f, 0.f};

#define ASTAGE(buf, k0)                                                          \
  {                                                                              \
    _Pragma("unroll")                                                            \
    for (int i = 0; i < 2; i++) {                                                \
      int q = w * 2 + i;   /* 4 global_load_lds per wave per buffer */           \
      load_lds16(Asrc + (size_t)(q * 8) * DIM + (k0), (char*)As[buf] + q * 1024);\
      load_lds16(Bsrc + (size_t)(q * 8) * DIM + (k0), (char*)Bs[buf] + q * 1024);\
    }                                                                            \
  }

#define ACOMPUTE(buf)                                                            \
  {                                                                              \
    _Pragma("unroll")                                                            \
    for (int kk = 0; kk < 2; kk++) {                                             \
      int sbase = kk * 4 + q4;                                                   \
      s16x8 af = *(const s16x8*)&As[buf][lds_idx(w * 16 + fr, sbase)];           \
      _Pragma("unroll")                                                          \
      for (int n = 0; n < 4; n++) {                                              \
        s16x8 bfv = *(const s16x8*)&Bs[buf][lds_idx(n * 16 + fr, sbase)];        \
        acc[n] = __builtin_amdgcn_mfma_f32_16x16x32_bf16(af, bfv, acc[n], 0, 0, 0); \
      }                                                                          \
    }                                                                            \
  }

  ASTAGE(0, 0);
  for (int t2 = 0; t2 < 12; t2 += 2) {
    ASTAGE(1, (t2 + 1) << 6);
    asm volatile("s_waitcnt vmcnt(4)" ::: "memory");
    __builtin_amdgcn_s_barrier();
    __builtin_amdgcn_sched_barrier(0);
    ACOMPUTE(0);
    __builtin_amdgcn_s_barrier();
    if (t2 + 2 < 12) {
      ASTAGE(0, (t2 + 2) << 6);
      asm volatile("s_waitcnt vmcnt(4)" ::: "memory");
    } else {
      asm volatile("s_waitcnt vmcnt(0)" ::: "memory");
    }
    __builtin_amdgcn_s_barrier();
    __builtin_amdgcn_sched_barrier(0);
    ACOMPUTE(1);
    __builtin_amdgcn_s_barrier();
  }
#undef ASTAGE
#undef ACOMPUTE

  const float* tq = tvec + (size_t)b * 1536 + h * 64;
  const float* tk = tq + DIM;
  const float* bq = bias + h * 64;
  const float* bk = bias + DIM + h * 64;
  int rbase = q4 * 4;
#pragma unroll
  for (int n = 0; n < 4; n++) {
    int e = n * 16 + fr;
    float bke = bk[e], tke = tk[e];
#pragma unroll
    for (int r = 0; r < 4; r++) {
      int d = w * 16 + rbase + r;
      float bqd = bq[d];
      float raw = acc[n][r] + bqd * tke + bke * tq[d] + 4096.f * bqd * bke;
      float val = 0.125f * raw;  // SCALE = 64^-0.5
      float sq = sqrtf(fabsf(val) + 1e-5f);
      sm[d * 65 + e] = val > 0.f ? sq : (val < 0.f ? -sq : 0.f);
    }
  }
  __syncthreads();
  {
    int d = t >> 2, qd = (t & 3) * 16;   // 4 lanes per row
    const float* row = &sm[d * 65];
    float mx = -1e30f;
#pragma unroll
    for (int e2 = 0; e2 < 16; e2++) mx = fmaxf(mx, row[qd + e2]);
    mx = fmaxf(mx, __shfl_xor(mx, 1));
    mx = fmaxf(mx, __shfl_xor(mx, 2));
    float sum = 0.f;
#pragma unroll
    for (int e2 = 0; e2 < 16; e2++) sum += __expf(row[qd + e2] - mx);
    sum += __shfl_xor(sum, 1);
    sum += __shfl_xor(sum, 2);
    float inv = 1.f / sum;
    float* o = outAttn + (((size_t)b * HEADS + h) * 64 + d) * 64;
#pragma unroll
    for (int e2 = 0; e2 < 16; e2++) o[qd + e2] = __expf(row[qd + e2] - mx) * inv;
  }
}

// ---------------- launch ----------------

extern "C" void kernel_launch(void* const* d_in, const int* in_sizes, int n_in,
                              void* d_out, int out_size, void* d_ws, size_t ws_size,
                              hipStream_t stream) {
  const float* x     = (const float*)d_in[0];
  const float* qkv_w = (const float*)d_in[1];
  const float* qkv_b = (const float*)d_in[2];
  const float* gamma = (const float*)d_in[3];
  const float* beta  = (const float*)d_in[4];
  float* out = (float*)d_out;
  float* ws  = (float*)d_ws;

  // ws layout: smalls + Wb + Gb + Pb = 40.3 MB; Xb (100.7 MB) at offset 40 MiB.
  float* sum_bc    = ws;                        // 12288 f
  float* sumsq_bc  = ws + 12288;                // 12288 f
  float* chanScale = ws + 24576;                // 768
  float* chanShift = ws + 25344;                // 768
  float* tvec      = ws + 26112;                // 24576 f
  u16* Wb = (u16*)(ws + 50688);                               // 1536*768 bf16
  u16* Gb = (u16*)((char*)d_ws + 2562048);                    // 16*768*768 bf16
  u16* Pb = (u16*)((char*)d_ws + 2562048 + 18874368);         // 16*768*768 bf16

  const bool wsRoom = ws_size >= (41943040ull + 100663296ull + 1024ull);
  u16* Xb = wsRoom ? (u16*)((char*)d_ws + 41943040) : (u16*)d_out;

  sums_cast_kernel<<<NB * DIM, 128, 0, stream>>>(x, sum_bc, sumsq_bc, Xb);
  finalize_kernel<<<3, 256, 0, stream>>>(sum_bc, sumsq_bc, gamma, beta, chanScale, chanShift);
  tvecw_kernel<<<2 * DIM, 64, 0, stream>>>(qkv_w, sum_bc, tvec, Wb);

  if (wsRoom) {
    // fused: 336 gram blocks (21 sym pairs x 16 batches, XCD-swizzled) + 256 BN blocks
    gemm_kernel<true><<<336 + 256, 256, 0, stream>>>(
        Xb, (long long)DIM * NPOS, Xb, (long long)DIM * NPOS, Gb, (long long)DIM * DIM,
        NPOS, NPOS, DIM, NPOS, 336, Xb, chanScale, chanShift, out);
  } else {
    // fallback: Xb parked in d_out -> gram first, then BN overwrites from fp32 x
    gemm_kernel<true><<<336, 256, 0, stream>>>(
        Xb, (long long)DIM * NPOS, Xb, (long long)DIM * NPOS, Gb, (long long)DIM * DIM,
        NPOS, NPOS, DIM, NPOS, 336, nullptr, chanScale, chanShift, nullptr);
    bn_kernel<<<2048, 256, 0, stream>>>(x, chanScale, chanShift, out);
  }

  // P_b = Wq · G_b  (G symmetric -> B rows = G rows); M=N=K=768, 128^2 tiles
  gemm_kernel<false><<<dim3(6, 6, NB), 256, 0, stream>>>(
      Wb, 0LL, Gb, (long long)DIM * DIM, Pb, (long long)DIM * DIM,
      DIM, DIM, DIM, DIM, 1 << 30, nullptr, nullptr, nullptr, nullptr);

  attn_kernel<<<dim3(HEADS, NB), 256, 0, stream>>>(Pb, Wb, qkv_b, tvec,
                                                   out + (size_t)NB * DIM * NPOS);
}

// Round 9
// 252.783 us; speedup vs baseline: 1.1019x; 1.1019x over previous
//
#include <hip/hip_runtime.h>
#include <hip/hip_bf16.h>

#define DIM 768
#define NB 16
#define NPOS 4096
#define HEADS 12

typedef unsigned short u16;
typedef __attribute__((ext_vector_type(4))) float f32x4;
typedef __attribute__((ext_vector_type(8))) short s16x8;
typedef __attribute__((ext_vector_type(4))) u16 u16x4;

static __device__ __forceinline__ u16 f2bf(float f) {
  __hip_bfloat16 h = __float2bfloat16(f);
  u16 u; __builtin_memcpy(&u, &h, 2); return u;
}
static __device__ __forceinline__ float bf2f(u16 u) {
  unsigned int x = ((unsigned int)u) << 16;
  float f; __builtin_memcpy(&f, &x, 4); return f;
}

// LDS tile layout: [rows][64 bf16]; 16B slot XOR-swizzled by (row&7).
// Reg-staged ds_write uses the same swizzle -> conflict-free write AND read (T2).
static __device__ __forceinline__ int lds_idx(int row, int slotf) {
  return row * 64 + (((slotf) ^ (row & 7)) << 3);   // ushort units
}

// ---------------- BN stats + fused cast to bf16 ----------------

__global__ __launch_bounds__(128) void sums_cast_kernel(const float* __restrict__ x,
                                                        float* __restrict__ sum_bc,
                                                        float* __restrict__ sumsq_bc,
                                                        u16* __restrict__ Xb) {
  int bc = blockIdx.x;  // b*DIM + c
  const float4* p = (const float4*)(x + (size_t)bc * NPOS);
  u16x4* ob = (u16x4*)(Xb + (size_t)bc * NPOS);
  int t = threadIdx.x;
  float s = 0.f, ss = 0.f;
  for (int i = t; i < NPOS / 4; i += 128) {
    float4 v = p[i];
    s  += v.x + v.y + v.z + v.w;
    ss += v.x * v.x + v.y * v.y + v.z * v.z + v.w * v.w;
    u16x4 hv = {f2bf(v.x), f2bf(v.y), f2bf(v.z), f2bf(v.w)};
    ob[i] = hv;
  }
  for (int off = 32; off; off >>= 1) { s += __shfl_down(s, off); ss += __shfl_down(ss, off); }
  __shared__ float red[4];
  int lane = t & 63, w = t >> 6;
  if (lane == 0) { red[w] = s; red[2 + w] = ss; }
  __syncthreads();
  if (t == 0) { sum_bc[bc] = red[0] + red[1]; sumsq_bc[bc] = red[2] + red[3]; }
}

__global__ void finalize_kernel(const float* __restrict__ sum_bc, const float* __restrict__ sumsq_bc,
                                const float* __restrict__ gamma, const float* __restrict__ beta,
                                float* __restrict__ chanScale, float* __restrict__ chanShift) {
  int c = blockIdx.x * blockDim.x + threadIdx.x;
  if (c >= DIM) return;
  float s = 0.f, ss = 0.f;
  for (int b = 0; b < NB; b++) { s += sum_bc[b * DIM + c]; ss += sumsq_bc[b * DIM + c]; }
  const float invn = 1.f / ((float)NB * (float)NPOS);
  float mean = s * invn;
  float var  = ss * invn - mean * mean;
  float rstd = rsqrtf(var + 1e-5f);
  float a = rstd * gamma[c];
  chanScale[c] = a;
  chanShift[c] = beta[c] - mean * a;
}

// standalone BN apply (fallback path only): reads fp32 x
__global__ __launch_bounds__(256) void bn_kernel(const float* __restrict__ x,
                                                 const float* __restrict__ chanScale,
                                                 const float* __restrict__ chanShift,
                                                 float* __restrict__ out) {
  const size_t n4 = (size_t)NB * DIM * NPOS / 4;
  const float4* x4 = (const float4*)x;
  float4* o4 = (float4*)out;
  for (size_t i = (size_t)blockIdx.x * blockDim.x + threadIdx.x; i < n4;
       i += (size_t)gridDim.x * blockDim.x) {
    float4 v = x4[i];
    int c = (int)((i >> 10) % DIM);
    float a = chanScale[c], sh = chanShift[c];
    v.x = fmaxf(fmaf(v.x, a, sh), 0.f);
    v.y = fmaxf(fmaf(v.y, a, sh), 0.f);
    v.z = fmaxf(fmaf(v.z, a, sh), 0.f);
    v.w = fmaxf(fmaf(v.w, a, sh), 0.f);
    o4[i] = v;
  }
}

// ------------- tvec (t[b][r] = W[r,:]·s_b) + fused cast of W rows 0..1535 -------------

__global__ __launch_bounds__(64) void tvecw_kernel(const float* __restrict__ W,
                                                   const float* __restrict__ sum_bc,
                                                   float* __restrict__ tvec,
                                                   u16* __restrict__ Wb) {
  int r = blockIdx.x;   // 0..1535
  int lane = threadIdx.x;
  const float* wr = W + (size_t)r * DIM;
  float acc[NB];
#pragma unroll
  for (int b = 0; b < NB; b++) acc[b] = 0.f;
#pragma unroll
  for (int j = 0; j < DIM / 64; j++) {
    int c = lane + j * 64;
    float wv = wr[c];
    Wb[(size_t)r * DIM + c] = f2bf(wv);
#pragma unroll
    for (int b = 0; b < NB; b++) acc[b] += wv * sum_bc[b * DIM + c];
  }
#pragma unroll
  for (int b = 0; b < NB; b++) {
    float v = acc[b];
    for (int off = 32; off; off >>= 1) v += __shfl_down(v, off);
    if (lane == 0) tvec[(size_t)b * 1536 + r] = v;
  }
}

// --- bf16 GEMM C = A·B^T, 128x128 tile, BK=64, REG-STAGED double-buffer (T14) ---
// Staging: global_load_dwordx4 -> VGPR (issued one half-step early, flies under
// compute) -> ds_write_b128 (XOR-swizzled). One lgkmcnt(0)+barrier per half-step;
// vmem never drains at a barrier.
// SYMM: 1-D grid; first nGram blocks = tile pairs ti<=tj (XCD-swizzled), write C
// and C^T; blocks >= nGram run a grid-stride BN-apply (HBM work overlapped).

template <bool SYMM>
__global__ __launch_bounds__(256) void gemm_kernel(
    const u16* __restrict__ A, long long strideA,
    const u16* __restrict__ B, long long strideB,
    u16* __restrict__ C, long long strideC,
    int lda, int ldb, int ldc, int K, int nGram,
    const u16* __restrict__ XbBn, const float* __restrict__ chanScale,
    const float* __restrict__ chanShift, float* __restrict__ outY) {
  __shared__ __align__(16) u16 As[2][128 * 64];
  __shared__ __align__(16) u16 Bs[2][128 * 64];

  int ti, tj, bz;
  if (SYMM) {
    if ((int)blockIdx.x >= nGram) {
      // ---- fused BN apply: y = relu(Xb*scale + shift), bf16 in / fp32 out ----
      int t = threadIdx.x;
      const size_t total8 = (size_t)NB * DIM * NPOS / 8;
      size_t stride = (size_t)(gridDim.x - nGram) * 256;
      const s16x8* xs = (const s16x8*)XbBn;
      float4* o4 = (float4*)outY;
      for (size_t i = (size_t)(blockIdx.x - nGram) * 256 + t; i < total8; i += stride) {
        s16x8 v = xs[i];
        int c = (int)((i >> 9) % DIM);   // 512 groups of 8 per (b,c) plane
        float a = chanScale[c], sh = chanShift[c];
        float4 o0, o1;
        o0.x = fmaxf(fmaf(bf2f((u16)v[0]), a, sh), 0.f);
        o0.y = fmaxf(fmaf(bf2f((u16)v[1]), a, sh), 0.f);
        o0.z = fmaxf(fmaf(bf2f((u16)v[2]), a, sh), 0.f);
        o0.w = fmaxf(fmaf(bf2f((u16)v[3]), a, sh), 0.f);
        o1.x = fmaxf(fmaf(bf2f((u16)v[4]), a, sh), 0.f);
        o1.y = fmaxf(fmaf(bf2f((u16)v[5]), a, sh), 0.f);
        o1.z = fmaxf(fmaf(bf2f((u16)v[6]), a, sh), 0.f);
        o1.w = fmaxf(fmaf(bf2f((u16)v[7]), a, sh), 0.f);
        o4[2 * i] = o0;
        o4[2 * i + 1] = o1;
      }
      return;
    }
    int bid = blockIdx.x;                       // nGram = 336, 336%8==0
    int swz = (bid & 7) * 42 + (bid >> 3);      // bijective XCD swizzle
    bz = swz / 21;
    int idx = swz % 21, rem = 6;
    ti = 0;
    while (idx >= rem) { idx -= rem; ti++; rem--; }
    tj = ti + idx;
  } else {
    ti = blockIdx.x; tj = blockIdx.y; bz = blockIdx.z;
  }
  const u16* Ab = A + (size_t)bz * strideA;
  const u16* Bb = B + (size_t)bz * strideB;
  u16* Cb = C + (size_t)bz * strideC;
  int ib = ti * 128, jb = tj * 128;

  int t = threadIdx.x, lane = t & 63;
  int w = t >> 6;
  int wr = (w >> 1) * 64, wc = (w & 1) * 64;
  int fr = lane & 15, q4 = lane >> 4;
  int srow = t >> 3;                 // 0..31 (covers rows srow + 32p)
  int sslot = t & 7;                 // linear 16B slot within the 128B row
  int wslot = sslot ^ (srow & 7);    // swizzled LDS slot (row&7 invariant under +32)

  // global staging source (coalesced: 8 consecutive threads = one 128B row)
  const u16* Asrc = Ab + (size_t)(ib + srow) * lda + sslot * 8;
  const u16* Bsrc = Bb + (size_t)(jb + srow) * ldb + sslot * 8;
  // LDS write offsets (ushort units)
  int lw = srow * 64 + wslot * 8;

  f32x4 acc[4][4];
#pragma unroll
  for (int m = 0; m < 4; m++)
#pragma unroll
    for (int n = 0; n < 4; n++) acc[m][n] = (f32x4){0.f, 0.f, 0.f, 0.f};

  s16x8 rA[4], rB[4];

#define GLOAD(k0)                                                               \
  {                                                                             \
    _Pragma("unroll")                                                           \
    for (int p = 0; p < 4; p++) {                                               \
      rA[p] = *(const s16x8*)(Asrc + (size_t)(p * 32) * lda + (k0));            \
      rB[p] = *(const s16x8*)(Bsrc + (size_t)(p * 32) * ldb + (k0));            \
    }                                                                           \
  }

#define DSW(buf)                                                                \
  {                                                                             \
    _Pragma("unroll")                                                           \
    for (int p = 0; p < 4; p++) {                                               \
      *(s16x8*)&As[buf][lw + p * 2048] = rA[p];                                 \
      *(s16x8*)&Bs[buf][lw + p * 2048] = rB[p];                                 \
    }                                                                           \
  }

#define COMPUTE(buf)                                                            \
  {                                                                             \
    _Pragma("unroll")                                                           \
    for (int kk = 0; kk < 2; kk++) {                                            \
      int sbase = kk * 4 + q4;                                                  \
      s16x8 af[4], bfv[4];                                                      \
      _Pragma("unroll")                                                         \
      for (int m = 0; m < 4; m++) af[m] = *(const s16x8*)&As[buf][lds_idx(wr + m * 16 + fr, sbase)]; \
      _Pragma("unroll")                                                         \
      for (int n = 0; n < 4; n++) bfv[n] = *(const s16x8*)&Bs[buf][lds_idx(wc + n * 16 + fr, sbase)]; \
      _Pragma("unroll")                                                         \
      for (int m = 0; m < 4; m++)                                               \
        _Pragma("unroll")                                                       \
        for (int n = 0; n < 4; n++)                                             \
          acc[m][n] = __builtin_amdgcn_mfma_f32_16x16x32_bf16(af[m], bfv[n], acc[m][n], 0, 0, 0); \
    }                                                                           \
  }

  const int nt = K >> 6;   // even for all uses (64 gram, 12 P)
  // prologue: tile0 -> buf0; issue tile1 loads
  GLOAD(0);
  DSW(0);                               // compiler inserts vmcnt wait at reg use
  GLOAD(64);
  asm volatile("s_waitcnt lgkmcnt(0)" ::: "memory");
  __builtin_amdgcn_s_barrier();
  __builtin_amdgcn_sched_barrier(0);
  for (int t2 = 0; t2 < nt; t2 += 2) {
    COMPUTE(0);
    DSW(1);                             // write tile t2+1 (regs); others read buf0 only
    if (t2 + 2 < nt) GLOAD((t2 + 2) << 6);
    asm volatile("s_waitcnt lgkmcnt(0)" ::: "memory");
    __builtin_amdgcn_s_barrier();
    __builtin_amdgcn_sched_barrier(0);
    COMPUTE(1);
    if (t2 + 2 < nt) {
      DSW(0);                           // write tile t2+2
      if (t2 + 3 < nt) GLOAD((t2 + 3) << 6);
    }
    asm volatile("s_waitcnt lgkmcnt(0)" ::: "memory");
    __builtin_amdgcn_s_barrier();
    __builtin_amdgcn_sched_barrier(0);
  }
#undef GLOAD
#undef DSW
#undef COMPUTE

  int rbase = q4 * 4;
#pragma unroll
  for (int m = 0; m < 4; m++)
#pragma unroll
    for (int n = 0; n < 4; n++)
#pragma unroll
      for (int r = 0; r < 4; r++) {
        int row = ib + wr + m * 16 + rbase + r;
        int col = jb + wc + n * 16 + fr;
        u16 v = f2bf(acc[m][n][r]);
        Cb[(size_t)row * ldc + col] = v;
        if (SYMM && ti != tj) Cb[(size_t)col * ldc + row] = v;
      }
}

// ---------- per-(b,h): attn = softmax(sign*sqrt(|S*(P·Wk^T + rank1)|+eps)) ----------
// Same reg-staged pipeline, 64x64 tiles (2 row-passes per thread).

__global__ __launch_bounds__(256) void attn_kernel(const u16* __restrict__ Pb,
                                                   const u16* __restrict__ Wb,
                                                   const float* __restrict__ bias,
                                                   const float* __restrict__ tvec,
                                                   float* __restrict__ outAttn) {
  int h = blockIdx.x, b = blockIdx.y;
  __shared__ __align__(16) u16 As[2][64 * 64];
  __shared__ __align__(16) u16 Bs[2][64 * 64];
  __shared__ float sm[64 * 65];
  const u16* Pa = Pb + ((size_t)b * DIM + h * 64) * DIM;
  const u16* Wk = Wb + (size_t)(DIM + h * 64) * DIM;

  int t = threadIdx.x, lane = t & 63, w = t >> 6;
  int fr = lane & 15, q4 = lane >> 4;
  int srow = t >> 3;                 // 0..31 (covers rows srow, srow+32)
  int sslot = t & 7;
  int wslot = sslot ^ (srow & 7);

  const u16* Asrc = Pa + (size_t)srow * DIM + sslot * 8;
  const u16* Bsrc = Wk + (size_t)srow * DIM + sslot * 8;
  int lw = srow * 64 + wslot * 8;

  f32x4 acc[4];
#pragma unroll
  for (int n = 0; n < 4; n++) acc[n] = (f32x4){0.f, 0.f, 0.f, 0.f};

  s16x8 rA[2], rB[2];

#define AGLOAD(k0)                                                              \
  {                                                                             \
    _Pragma("unroll")                                                           \
    for (int p = 0; p < 2; p++) {                                               \
      rA[p] = *(const s16x8*)(Asrc + (size_t)(p * 32) * DIM + (k0));            \
      rB[p] = *(const s16x8*)(Bsrc + (size_t)(p * 32) * DIM + (k0));            \
    }                                                                           \
  }

#define ADSW(buf)                                                               \
  {                                                                             \
    _Pragma("unroll")                                                           \
    for (int p = 0; p < 2; p++) {                                               \
      *(s16x8*)&As[buf][lw + p * 2048] = rA[p];                                 \
      *(s16x8*)&Bs[buf][lw + p * 2048] = rB[p];                                 \
    }                                                                           \
  }

#define ACOMPUTE(buf)                                                           \
  {                                                                             \
    _Pragma("unroll")                                                           \
    for (int kk = 0; kk < 2; kk++) {                                            \
      int sbase = kk * 4 + q4;                                                  \
      s16x8 af = *(const s16x8*)&As[buf][lds_idx(w * 16 + fr, sbase)];          \
      _Pragma("unroll")                                                         \
      for (int n = 0; n < 4; n++) {                                             \
        s16x8 bfv = *(const s16x8*)&Bs[buf][lds_idx(n * 16 + fr, sbase)];       \
        acc[n] = __builtin_amdgcn_mfma_f32_16x16x32_bf16(af, bfv, acc[n], 0, 0, 0); \
      }                                                                         \
    }                                                                           \
  }

  AGLOAD(0);
  ADSW(0);
  AGLOAD(64);
  asm volatile("s_waitcnt lgkmcnt(0)" ::: "memory");
  __builtin_amdgcn_s_barrier();
  __builtin_amdgcn_sched_barrier(0);
  for (int t2 = 0; t2 < 12; t2 += 2) {
    ACOMPUTE(0);
    ADSW(1);
    if (t2 + 2 < 12) AGLOAD((t2 + 2) << 6);
    asm volatile("s_waitcnt lgkmcnt(0)" ::: "memory");
    __builtin_amdgcn_s_barrier();
    __builtin_amdgcn_sched_barrier(0);
    ACOMPUTE(1);
    if (t2 + 2 < 12) {
      ADSW(0);
      if (t2 + 3 < 12) AGLOAD((t2 + 3) << 6);
    }
    asm volatile("s_waitcnt lgkmcnt(0)" ::: "memory");
    __builtin_amdgcn_s_barrier();
    __builtin_amdgcn_sched_barrier(0);
  }
#undef AGLOAD
#undef ADSW
#undef ACOMPUTE

  const float* tq = tvec + (size_t)b * 1536 + h * 64;
  const float* tk = tq + DIM;
  const float* bq = bias + h * 64;
  const float* bk = bias + DIM + h * 64;
  int rbase = q4 * 4;
#pragma unroll
  for (int n = 0; n < 4; n++) {
    int e = n * 16 + fr;
    float bke = bk[e], tke = tk[e];
#pragma unroll
    for (int r = 0; r < 4; r++) {
      int d = w * 16 + rbase + r;
      float bqd = bq[d];
      float raw = acc[n][r] + bqd * tke + bke * tq[d] + 4096.f * bqd * bke;
      float val = 0.125f * raw;  // SCALE = 64^-0.5
      float sq = sqrtf(fabsf(val) + 1e-5f);
      sm[d * 65 + e] = val > 0.f ? sq : (val < 0.f ? -sq : 0.f);
    }
  }
  __syncthreads();
  {
    int d = t >> 2, qd = (t & 3) * 16;   // 4 lanes per row
    const float* row = &sm[d * 65];
    float mx = -1e30f;
#pragma unroll
    for (int e2 = 0; e2 < 16; e2++) mx = fmaxf(mx, row[qd + e2]);
    mx = fmaxf(mx, __shfl_xor(mx, 1));
    mx = fmaxf(mx, __shfl_xor(mx, 2));
    float sum = 0.f;
#pragma unroll
    for (int e2 = 0; e2 < 16; e2++) sum += __expf(row[qd + e2] - mx);
    sum += __shfl_xor(sum, 1);
    sum += __shfl_xor(sum, 2);
    float inv = 1.f / sum;
    float* o = outAttn + (((size_t)b * HEADS + h) * 64 + d) * 64;
#pragma unroll
    for (int e2 = 0; e2 < 16; e2++) o[qd + e2] = __expf(row[qd + e2] - mx) * inv;
  }
}

// ---------------- launch ----------------

extern "C" void kernel_launch(void* const* d_in, const int* in_sizes, int n_in,
                              void* d_out, int out_size, void* d_ws, size_t ws_size,
                              hipStream_t stream) {
  const float* x     = (const float*)d_in[0];
  const float* qkv_w = (const float*)d_in[1];
  const float* qkv_b = (const float*)d_in[2];
  const float* gamma = (const float*)d_in[3];
  const float* beta  = (const float*)d_in[4];
  float* out = (float*)d_out;
  float* ws  = (float*)d_ws;

  // ws layout: smalls + Wb + Gb + Pb = 40.3 MB; Xb (100.7 MB) at offset 40 MiB.
  float* sum_bc    = ws;                        // 12288 f
  float* sumsq_bc  = ws + 12288;                // 12288 f
  float* chanScale = ws + 24576;                // 768
  float* chanShift = ws + 25344;                // 768
  float* tvec      = ws + 26112;                // 24576 f
  u16* Wb = (u16*)(ws + 50688);                               // 1536*768 bf16
  u16* Gb = (u16*)((char*)d_ws + 2562048);                    // 16*768*768 bf16
  u16* Pb = (u16*)((char*)d_ws + 2562048 + 18874368);         // 16*768*768 bf16

  const bool wsRoom = ws_size >= (41943040ull + 100663296ull + 1024ull);
  u16* Xb = wsRoom ? (u16*)((char*)d_ws + 41943040) : (u16*)d_out;

  sums_cast_kernel<<<NB * DIM, 128, 0, stream>>>(x, sum_bc, sumsq_bc, Xb);
  finalize_kernel<<<3, 256, 0, stream>>>(sum_bc, sumsq_bc, gamma, beta, chanScale, chanShift);
  tvecw_kernel<<<2 * DIM, 64, 0, stream>>>(qkv_w, sum_bc, tvec, Wb);

  if (wsRoom) {
    // fused: 336 gram blocks (21 sym pairs x 16 batches, XCD-swizzled) + 256 BN blocks
    gemm_kernel<true><<<336 + 256, 256, 0, stream>>>(
        Xb, (long long)DIM * NPOS, Xb, (long long)DIM * NPOS, Gb, (long long)DIM * DIM,
        NPOS, NPOS, DIM, NPOS, 336, Xb, chanScale, chanShift, out);
  } else {
    // fallback: Xb parked in d_out -> gram first, then BN overwrites from fp32 x
    gemm_kernel<true><<<336, 256, 0, stream>>>(
        Xb, (long long)DIM * NPOS, Xb, (long long)DIM * NPOS, Gb, (long long)DIM * DIM,
        NPOS, NPOS, DIM, NPOS, 336, nullptr, chanScale, chanShift, nullptr);
    bn_kernel<<<2048, 256, 0, stream>>>(x, chanScale, chanShift, out);
  }

  // P_b = Wq · G_b  (G symmetric -> B rows = G rows); M=N=K=768, 128^2 tiles
  gemm_kernel<false><<<dim3(6, 6, NB), 256, 0, stream>>>(
      Wb, 0LL, Gb, (long long)DIM * DIM, Pb, (long long)DIM * DIM,
      DIM, DIM, DIM, DIM, 1 << 30, nullptr, nullptr, nullptr, nullptr);

  attn_kernel<<<dim3(HEADS, NB), 256, 0, stream>>>(Pb, Wb, qkv_b, tvec,
                                                   out + (size_t)NB * DIM * NPOS);
}